// Round 4
// baseline (127.276 us; speedup 1.0000x reference)
//
#include <hip/hip_runtime.h>
#include <math.h>

#define DIM  512
#define H2   512
#define BSZ  384

// ---------------------------------------------------------------------------
// ws layout (floats):
//   hmu : 384*512  @ 0        relu(x@w1mu + b1mu)
//   hlv : 384*512  @ 196608
//   gmu : 384*512  @ 393216   hmu@w2mu (no bias)
//   glv : 384*512  @ 589824
//   m1p : 6*512    @ 786432   y column-sum partials
//   m2p : 6*512    @ 789504   y column-sumsq partials
//   part: 192 dbl  @ 793600   (byte 3174400, 8B aligned)
//   sync: 97 uint  @ 793984   [0]=final ctr, [1..96]=pair counters
//                              (all zeroed by K1 block 192 each launch)
//
// Round-4 structure: two kernels.
//   K1: unchanged round-0 GEMM (32x64 tile, 2x4 micro — proven fastest) for
//       layer 1, both branches (192 blocks) + 6 y-moment blocks; block 192
//       zeroes the 97 sync words. 198x256.
//   K2: layer-2 GEMMs (192 blocks, r0-GEMM bit-exact) + per-tile PAIR sync
//       (mu-block <-> lv-block of same tile idx) + in-kernel epilogue (each
//       pair member does half its tile, 1 float4/thread) + fence+counter
//       final reduce (proven since round 1). K3 launch eliminated.
// ---------------------------------------------------------------------------

template<bool RELU>
__device__ __forceinline__ void gemm_tile(
    const float* __restrict__ A, const float* __restrict__ B,
    const float* __restrict__ bias, float* __restrict__ C,
    int m0, int n0,
    float (*As)[34], float (*Bs)[64])
{
    const int tid = threadIdx.x;
    const int tx = tid & 15;        // col group: n0 + tx*4
    const int ty = tid >> 4;        // rows: m0 + ty*2 + {0,1}

    const int r_a  = tid >> 3;      // 0..31  A-tile row
    const int kg_a = tid & 7;       // 0..7   A-tile k-group (4 floats)
    const int kr_b = tid >> 4;      // 0..15  B-tile row (and +16)
    const int cg_b = tid & 15;      // 0..15  B-tile col group

    float acc[2][4] = {};

    float4 a_pf  = *(const float4*)&A[(size_t)(m0 + r_a) * 512 + kg_a * 4];
    float4 b_pf0 = *(const float4*)&B[(size_t)kr_b        * 512 + n0 + cg_b * 4];
    float4 b_pf1 = *(const float4*)&B[(size_t)(kr_b + 16) * 512 + n0 + cg_b * 4];

    for (int it = 0; it < 16; ++it) {
        __syncthreads();
        {
            float av[4];
            *(float4*)av = a_pf;
            #pragma unroll
            for (int j = 0; j < 4; ++j) As[kg_a * 4 + j][r_a] = av[j];
            *(float4*)&Bs[kr_b][cg_b * 4]      = b_pf0;
            *(float4*)&Bs[kr_b + 16][cg_b * 4] = b_pf1;
        }
        __syncthreads();

        if (it < 15) {  // next-iter loads; latency overlaps compute below
            const int k0n = (it + 1) * 32;
            a_pf  = *(const float4*)&A[(size_t)(m0 + r_a) * 512 + k0n + kg_a * 4];
            b_pf0 = *(const float4*)&B[(size_t)(k0n + kr_b)      * 512 + n0 + cg_b * 4];
            b_pf1 = *(const float4*)&B[(size_t)(k0n + kr_b + 16) * 512 + n0 + cg_b * 4];
        }

        #pragma unroll
        for (int kk = 0; kk < 32; ++kk) {
            const float a0 = As[kk][ty * 2 + 0];
            const float a1 = As[kk][ty * 2 + 1];
            const float4 bv = *(const float4*)&Bs[kk][tx * 4];
            acc[0][0] += a0 * bv.x; acc[0][1] += a0 * bv.y;
            acc[0][2] += a0 * bv.z; acc[0][3] += a0 * bv.w;
            acc[1][0] += a1 * bv.x; acc[1][1] += a1 * bv.y;
            acc[1][2] += a1 * bv.z; acc[1][3] += a1 * bv.w;
        }
    }

    float bb[4] = {0.f, 0.f, 0.f, 0.f};
    if (RELU) *(float4*)bb = *(const float4*)&bias[n0 + tx * 4];
    #pragma unroll
    for (int i = 0; i < 2; ++i) {
        float4 o;
        if (RELU) {
            o.x = fmaxf(acc[i][0] + bb[0], 0.f);
            o.y = fmaxf(acc[i][1] + bb[1], 0.f);
            o.z = fmaxf(acc[i][2] + bb[2], 0.f);
            o.w = fmaxf(acc[i][3] + bb[3], 0.f);
        } else {
            o.x = acc[i][0]; o.y = acc[i][1]; o.z = acc[i][2]; o.w = acc[i][3];
        }
        *(float4*)&C[(size_t)(m0 + ty * 2 + i) * 512 + n0 + tx * 4] = o;
    }
}

// Kernel 1: layer-1 GEMMs for both branches (blocks 0..191) + y column-moment
// partial blocks (192..197). Block 192 zeroes all 97 sync words.
__global__ __launch_bounds__(256) void k_layer1(
    const float* __restrict__ x,
    const float* __restrict__ w1mu, const float* __restrict__ b1mu,
    const float* __restrict__ w1lv, const float* __restrict__ b1lv,
    const float* __restrict__ y,
    float* __restrict__ hmu, float* __restrict__ hlv,
    float* __restrict__ m1p, float* __restrict__ m2p,
    unsigned* __restrict__ sync_)
{
    __shared__ float As[32][34];
    __shared__ float Bs[32][64];

    const int b = blockIdx.x;
    const int tid = threadIdx.x;

    if (b >= 192) {
        __shared__ float r1[2][512];
        __shared__ float r2[2][512];
        const int sb = b - 192;
        if (sb == 0 && tid < 97) sync_[tid] = 0u;   // reset K2 sync words
        const int c4 = tid & 127;
        const int rh = tid >> 7;
        const int r0 = sb * 64 + rh * 32;
        float s1[4] = {0.f, 0.f, 0.f, 0.f};
        float s2[4] = {0.f, 0.f, 0.f, 0.f};
        for (int r = 0; r < 32; ++r) {
            float v[4];
            *(float4*)v = *(const float4*)&y[(size_t)(r0 + r) * 512 + c4 * 4];
            #pragma unroll
            for (int j = 0; j < 4; ++j) { s1[j] += v[j]; s2[j] += v[j] * v[j]; }
        }
        #pragma unroll
        for (int j = 0; j < 4; ++j) { r1[rh][c4 * 4 + j] = s1[j]; r2[rh][c4 * 4 + j] = s2[j]; }
        __syncthreads();
        if (rh == 0) {
            float4 o1, o2;
            o1.x = s1[0] + r1[1][c4 * 4 + 0]; o1.y = s1[1] + r1[1][c4 * 4 + 1];
            o1.z = s1[2] + r1[1][c4 * 4 + 2]; o1.w = s1[3] + r1[1][c4 * 4 + 3];
            o2.x = s2[0] + r2[1][c4 * 4 + 0]; o2.y = s2[1] + r2[1][c4 * 4 + 1];
            o2.z = s2[2] + r2[1][c4 * 4 + 2]; o2.w = s2[3] + r2[1][c4 * 4 + 3];
            *(float4*)&m1p[sb * 512 + c4 * 4] = o1;
            *(float4*)&m2p[sb * 512 + c4 * 4] = o2;
        }
        return;
    }

    const int branch = b >= 96 ? 1 : 0;
    const int idx = branch ? b - 96 : b;
    const int m0 = (idx >> 3) * 32;   // 12 row tiles
    const int n0 = (idx & 7) * 64;    // 8 col tiles

    if (branch == 0)
        gemm_tile<true>(x, w1mu, b1mu, hmu, m0, n0, As, Bs);
    else
        gemm_tile<true>(x, w1lv, b1lv, hlv, m0, n0, As, Bs);
}

// Kernel 2: layer-2 GEMMs + pair-synced epilogue + final reduction.
// 192 blocks x 256 threads. Block b<96 = mu tile idx b; block b>=96 = lv tile
// idx b-96. After writing its g-tile, each block rendezvouses with its pair
// via sync_[1+idx], then epilogues half the tile (mu: rows +0..15, lv: rows
// +16..31; 1 float4/thread). Partials -> fence+counter last-block reduce.
__global__ __launch_bounds__(256) void k2_fused(
    const float* __restrict__ hmu, const float* __restrict__ hlv,
    const float* __restrict__ w2mu, const float* __restrict__ w2lv,
    const float* __restrict__ b2mu, const float* __restrict__ b2lv,
    const float* __restrict__ y,
    const float* __restrict__ m1p, const float* __restrict__ m2p,
    float* __restrict__ gmu, float* __restrict__ glv,
    double* __restrict__ partials, unsigned* __restrict__ sync_,
    float* __restrict__ out)
{
    __shared__ float As[32][34];
    __shared__ float Bs[32][64];
    __shared__ double wsum[4];
    __shared__ int lastFlag;

    const int b   = blockIdx.x;
    const int tid = threadIdx.x;
    const int branch = b >= 96 ? 1 : 0;
    const int idx = branch ? b - 96 : b;
    const int m0 = (idx >> 3) * 32;
    const int n0 = (idx & 7) * 64;

    if (branch == 0)
        gemm_tile<false>(hmu, w2mu, nullptr, gmu, m0, n0, As, Bs);
    else
        gemm_tile<false>(hlv, w2lv, nullptr, glv, m0, n0, As, Bs);

    // ---- pair rendezvous (proven fence+atomic pattern; all 192 blocks are
    // co-resident at 256 CUs, so the spin cannot deadlock) ----
    unsigned* pc = sync_ + 1 + idx;
    __syncthreads();                 // drains vmcnt: all C writes complete
    if (tid == 0) {
        __threadfence();             // release our g-tile device-wide
        atomicAdd(pc, 1u);
        while (atomicAdd(pc, 0u) < 2u) __builtin_amdgcn_s_sleep(2);
    }
    __syncthreads();
    __threadfence();                 // acquire partner's g-tile

    // ---- epilogue: my half of the 32x64 tile ----
    const int r  = tid >> 4;         // 0..15
    const int c4 = tid & 15;         // 0..15
    const int row = m0 + branch * 16 + r;
    const int col = n0 + c4 * 4;
    const size_t off = (size_t)row * 512 + col;

    float gm[4], gl[4], yv[4], bm[4], bl[4], s1[4], s2[4];
    *(float4*)gm = *(const float4*)&gmu[off];
    *(float4*)gl = *(const float4*)&glv[off];
    *(float4*)yv = *(const float4*)&y[off];
    *(float4*)bm = *(const float4*)&b2mu[col];
    *(float4*)bl = *(const float4*)&b2lv[col];
    #pragma unroll
    for (int j = 0; j < 4; ++j) { s1[j] = 0.f; s2[j] = 0.f; }
    #pragma unroll
    for (int p = 0; p < 6; ++p) {
        float p1[4], p2[4];
        *(float4*)p1 = *(const float4*)&m1p[p * 512 + col];
        *(float4*)p2 = *(const float4*)&m2p[p * 512 + col];
        #pragma unroll
        for (int j = 0; j < 4; ++j) { s1[j] += p1[j]; s2[j] += p2[j]; }
    }

    const float inv_b = 1.0f / (float)BSZ;
    float tsum = 0.f;
    #pragma unroll
    for (int j = 0; j < 4; ++j) {
        const float m1 = s1[j] * inv_b;
        const float m2 = s2[j] * inv_b;
        const float mu = gm[j] + bm[j];
        const float lv = tanhf(gl[j] + bl[j]);
        const float iv = expf(-lv);
        tsum += iv * ((yv[j] * yv[j] - m2) + 2.f * mu * (m1 - yv[j]));
    }

    // block reduction
    float s = tsum;
    #pragma unroll
    for (int o = 32; o > 0; o >>= 1) s += __shfl_down(s, o);
    if ((tid & 63) == 0) wsum[tid >> 6] = (double)s;
    __syncthreads();
    if (tid == 0) {
        partials[b] = wsum[0] + wsum[1] + wsum[2] + wsum[3];
        __threadfence();
        lastFlag = (atomicAdd(&sync_[0], 1u) == 191u);
    }
    __syncthreads();

    if (lastFlag) {
        __threadfence();  // acquire: make all partials visible
        if (tid < 64) {
            double v = partials[tid] + partials[tid + 64] + partials[tid + 128];
            #pragma unroll
            for (int o = 32; o > 0; o >>= 1) v += __shfl_down(v, o);
            if (tid == 0) {
                // C0 = log1p(exp(-20)/383) — the broadcast-bug logsumexp constant
                const double C0 = 5.381602146862063e-12;
                out[0] = (float)(-0.5 * v / (double)BSZ - C0);
            }
        }
    }
}

extern "C" void kernel_launch(void* const* d_in, const int* in_sizes, int n_in,
                              void* d_out, int out_size, void* d_ws, size_t ws_size,
                              hipStream_t stream) {
    const float* x    = (const float*)d_in[0];
    const float* y    = (const float*)d_in[1];
    const float* w1mu = (const float*)d_in[2];
    const float* b1mu = (const float*)d_in[3];
    const float* w2mu = (const float*)d_in[4];
    const float* b2mu = (const float*)d_in[5];
    const float* w1lv = (const float*)d_in[6];
    const float* b1lv = (const float*)d_in[7];
    const float* w2lv = (const float*)d_in[8];
    const float* b2lv = (const float*)d_in[9];
    float* out = (float*)d_out;

    float* ws = (float*)d_ws;
    float* hmu = ws;
    float* hlv = ws + 196608;
    float* gmu = ws + 393216;
    float* glv = ws + 589824;
    float* m1p = ws + 786432;
    float* m2p = ws + 789504;
    double* partials = (double*)(ws + 793600);
    unsigned* sync_ = (unsigned*)(ws + 793984);

    k_layer1<<<198, 256, 0, stream>>>(x, w1mu, b1mu, w1lv, b1lv, y,
                                      hmu, hlv, m1p, m2p, sync_);
    k2_fused<<<192, 256, 0, stream>>>(hmu, hlv, w2mu, w2lv, b2mu, b2lv, y,
                                      m1p, m2p, gmu, glv, partials, sync_, out);
}